// Round 2
// baseline (113.738 us; speedup 1.0000x reference)
//
#include <hip/hip_runtime.h>
#include <stdint.h>

#define NPTS 2048

// ---- workspace layout (bytes) ----
// Bp fragment-ordered for 32x32x16 MFMA: [z][cb=8][s=64][kc=2][frag 1KB].
// cb = global-col>>5 (256 cols = {f*gx,f*gy,f*gz,f} x 64j); kc = b-halfchunk (16 b each).
// Frag lane l (l&31 = col within 32-strip, l>>5 = k-half) holds 8 bf16 at k = (l>>5)*8..+8.
#define BP_OFF    0ULL
#define BP_BYTES  (8ULL * 8 * 64 * 2 * 1024)   // 8 MB
#define W2F_OFF   (BP_OFF + BP_BYTES)
#define W2F_BYTES (24ULL * 1024)               // frags kb0..5 x cb0..3
#define WXF_OFF   (W2F_OFF + W2F_BYTES)
#define WXF_BYTES (24ULL * 1024)               // frags kb0..1 x cb0..11
// Mask words: [z][at32=32][kw=64][64 dwords]; dword (r&15)*4+((r>>4)&3) = word for row r.
#define MW_OFF    (WXF_OFF + WXF_BYTES)
#define MW_BYTES  (8ULL * 32 * 64 * 256)       // 4 MB  (total ~12.4 MB)

typedef __attribute__((ext_vector_type(8))) short bf16x8;
typedef __attribute__((ext_vector_type(4))) float f32x4;
typedef __attribute__((ext_vector_type(16))) float f32x16;
typedef __attribute__((ext_vector_type(4))) unsigned int u32x4;

__device__ __forceinline__ unsigned f2bf(float f) {
  union { float f; unsigned u; } v; v.f = f;
  return (v.u + 0x7FFFu + ((v.u >> 16) & 1u)) >> 16;  // RNE
}

__device__ __forceinline__ bf16x8 pack8(const float4 a, const float4 b) {
  u32x4 r;
  r[0] = f2bf(a.x) | (f2bf(a.y) << 16);
  r[1] = f2bf(a.z) | (f2bf(a.w) << 16);
  r[2] = f2bf(b.x) | (f2bf(b.y) << 16);
  r[3] = f2bf(b.z) | (f2bf(b.w) << 16);
  union { u32x4 u; bf16x8 h; } c; c.u = r; return c.h;
}

// 8 mask bits -> 8 bf16 (1.0/0.0): bit-deposit mul + v_perm + mul. (R9-verified)
__device__ __forceinline__ bf16x8 unpack_mask(unsigned mq) {
  const unsigned dep0 = ((mq & 15u) * 0x204081u) & 0x01010101u;        // bits0-3 -> bytes
  const unsigned dep1 = (((mq >> 4) & 15u) * 0x204081u) & 0x01010101u; // bits4-7
  u32x4 aw;
  aw[0] = __builtin_amdgcn_perm(dep0, 0u, 0x0C050C04u) * 0x3F80u;
  aw[1] = __builtin_amdgcn_perm(dep0, 0u, 0x0C070C06u) * 0x3F80u;
  aw[2] = __builtin_amdgcn_perm(dep1, 0u, 0x0C050C04u) * 0x3F80u;
  aw[3] = __builtin_amdgcn_perm(dep1, 0u, 0x0C070C06u) * 0x3F80u;
  union { u32x4 u; bf16x8 h; } cv; cv.u = aw;
  return cv.h;
}

// ========== K1: Bp frags (32x32x16 layout) + weight frags + mask bitwords (verified) ==========
__global__ __launch_bounds__(256, 2) void k1_prep(const float* __restrict__ feat,
                                                  const float* __restrict__ geom,
                                                  const float* __restrict__ Wk,
                                                  unsigned char* __restrict__ ws) {
  const int blk = blockIdx.x, t = threadIdx.x;
  if (blk < 512) {
    const int z = blk >> 6, s = blk & 63;       // 32 b-points per s-chunk
    __shared__ float FT[64][37];                // F^T[j][k]
    __shared__ float g[96];                     // b-geometry [32][3]
    __shared__ float gxp[2048], gyp[2048], gzp[2048];  // z geometry, swizzled p'=(p&7)*256+(p>>3)
    const float* fz = feat + ((size_t)z * NPTS + s * 32) * 64;
    const float* gz = geom + (size_t)z * NPTS * 3;
    {
      const int row = t >> 3, j0 = (t & 7) << 3;
      const float4 v0 = *(const float4*)&fz[row * 64 + j0];
      const float4 v1 = *(const float4*)&fz[row * 64 + j0 + 4];
      FT[j0 + 0][row] = v0.x; FT[j0 + 1][row] = v0.y;
      FT[j0 + 2][row] = v0.z; FT[j0 + 3][row] = v0.w;
      FT[j0 + 4][row] = v1.x; FT[j0 + 5][row] = v1.y;
      FT[j0 + 6][row] = v1.z; FT[j0 + 7][row] = v1.w;
    }
    if (t < 96) g[t] = gz[s * 96 + t];
    {  // stage geometry planes: thread reads 24 contiguous floats (8 points)
      float v[24];
#pragma unroll
      for (int i = 0; i < 6; ++i) *(float4*)&v[i * 4] = *(const float4*)&gz[t * 24 + i * 4];
#pragma unroll
      for (int i = 0; i < 8; ++i) {
        const int pp = i * 256 + t;             // swizzled slot (conflict-free)
        gxp[pp] = v[i * 3 + 0]; gyp[pp] = v[i * 3 + 1]; gzp[pp] = v[i * 3 + 2];
      }
    }
    __syncthreads();

    {  // ---- Bp build, 32x32x16 B-frag layout ----
      const int w = t >> 6, L = t & 63;
      const int nn = L >> 2, k0 = (L & 3) * 8;
      const int j = w * 16 + nn;
      float f[8];
#pragma unroll
      for (int i = 0; i < 8; ++i) f[i] = FT[j][k0 + i];
      float gx[3][8];
#pragma unroll
      for (int x = 0; x < 3; ++x)
#pragma unroll
        for (int i = 0; i < 8; ++i) gx[x][i] = g[(k0 + i) * 3 + x];
      // 32x32 frag addressing: cb = it*2 + (w>>1); kc = k0>>4; lane = h*32 + (w&1)*16 + nn
      const int kc = (L & 3) >> 1, h = (L & 3) & 1;
      const int lane16 = h * 32 + (w & 1) * 16 + nn;
      unsigned char* base = ws + BP_OFF + (size_t)z * 1048576 + (size_t)(w >> 1) * 131072 +
                            (size_t)s * 2048 + (size_t)kc * 1024 + (size_t)lane16 * 16;
#pragma unroll
      for (int it = 0; it < 4; ++it) {          // x = it; col group it
        u32x4 pv;
#pragma unroll
        for (int p = 0; p < 4; ++p) {
          float f0 = f[2 * p], f1 = f[2 * p + 1];
          if (it < 3) { f0 *= gx[it][2 * p]; f1 *= gx[it][2 * p + 1]; }
          pv[p] = f2bf(f0) | (f2bf(f1) << 16);
        }
        *(u32x4*)(base + (size_t)it * 262144) = pv;   // cb step = 2 frag-groups = 256 KB
      }
    }

    {  // ---- mask bitwords: rows t*8..+8 vs b = s*32..+32 ----
      float ax[8], ay[8], az[8];
#pragma unroll
      for (int i = 0; i < 8; ++i) {
        const int pp = i * 256 + t;
        ax[i] = gxp[pp]; ay[i] = gyp[pp]; az[i] = gzp[pp];
      }
      unsigned bits[8] = {0, 0, 0, 0, 0, 0, 0, 0};
      for (int j = 0; j < 32; ++j) {
        const float bx = g[j * 3 + 0], by = g[j * 3 + 1], bz = g[j * 3 + 2];
#pragma unroll
        for (int i = 0; i < 8; ++i) {
          const float d0 = bx - ax[i], d1 = by - ay[i], d2 = bz - az[i];
          const float n2 = fmaf(d2, d2, fmaf(d1, d1, d0 * d0));
          bits[i] |= (n2 < 1.0f ? 1u : 0u) << j;
        }
      }
      unsigned int* mw = (unsigned int*)(ws + MW_OFF);
#pragma unroll
      for (int i = 0; i < 8; ++i) {
        const int r = t * 8 + i;
        mw[(((size_t)z * 32 + (r >> 6)) * 64 + s) * 64 + (r & 15) * 4 + ((r >> 4) & 3)] = bits[i];
      }
    }
  } else if (blk == 512) {   // W2F frags
    for (int e = t; e < 1536; e += 256) {
      const int frag = e >> 6, lp = e & 63, nn = lp >> 2, qd = lp & 3;
      const int kb = frag >> 2, cb = frag & 3;
      u32x4 pv;
#pragma unroll
      for (int p = 0; p < 4; ++p) {
        const int k0 = kb * 32 + qd * 8 + 2 * p;
        const float v0 = Wk[(k0 >> 6) * 4096 + (cb * 16 + nn) * 64 + (k0 & 63)];
        const float v1 = Wk[((k0 + 1) >> 6) * 4096 + (cb * 16 + nn) * 64 + ((k0 + 1) & 63)];
        pv[p] = f2bf(v0) | (f2bf(v1) << 16);
      }
      *(u32x4*)(ws + W2F_OFF + (size_t)frag * 1024 + lp * 16) = pv;
    }
  } else {                   // WXF frags
    for (int e = t; e < 1536; e += 256) {
      const int frag = e >> 6, lp = e & 63, nn = lp >> 2, qd = lp & 3;
      const int kb = frag / 12, cb = frag % 12, xi = cb * 16 + nn;
      u32x4 pv;
#pragma unroll
      for (int p = 0; p < 4; ++p) {
        const int k0 = kb * 32 + qd * 8 + 2 * p;
        const float v0 = Wk[(xi >> 6) * 4096 + (xi & 63) * 64 + k0];
        const float v1 = Wk[(xi >> 6) * 4096 + (xi & 63) * 64 + k0 + 1];
        pv[p] = f2bf(v0) | (f2bf(v1) << 16);
      }
      *(u32x4*)(ws + WXF_OFF + (size_t)frag * 1024 + lp * 16) = pv;
    }
  }
}

// ========== K2: 128-row blocks, LDS-shared mask A-frags, halved Bp L2 traffic ==========
// grid 128 = (z = bx&7 -> XCD-resident Bp, at = bx>>3 in 0..15). 512 thr = 8 waves.
// Wave w: ALL 128 rows (4 mtiles) x 32-col strip cb=w. A-frags produced cooperatively:
// wave w unpacks frag-type (mt=w>>1, kc=w&1) at its own lane (bit-identical to the
// private unpack) into a 64KB dbuf aliased with Ct. 1 barrier per 8-step group.
__global__ __launch_bounds__(512, 1) void k2_gemm(const float* __restrict__ geom,
                                                  const unsigned char* __restrict__ ws,
                                                  float* __restrict__ out) {
  __shared__ __align__(16) float Ct[128 * 256];           // 128 KB; K-loop aliases as A dbuf
  unsigned char* const ab0 = (unsigned char*)Ct;          // bytes [0, 64K)
  unsigned char* const ab1 = (unsigned char*)Ct + 65536;  // bytes [64K, 128K)

  const int t = threadIdx.x, lane = t & 63, w = t >> 6;   // w = 0..7
  const int l31 = lane & 31;
  const int h8 = (lane >> 5) << 3;                        // k-half shift (0 or 8)
  const int quad = (lane >> 4) & 3, n = lane & 15;        // epilogue 16x16 mapping
  const int fragoff = n * 64 + quad * 16;
  const int bx = blockIdx.x;
  const int z = bx & 7, at = bx >> 3, a0 = at * 128;

  const unsigned char* bpz = ws + BP_OFF + (size_t)z * 1048576 + (size_t)w * 131072;

  // producer assignment: wave w -> frag-type (mt = w>>1, kc = w&1), its own lane slot
  const int pmt = w >> 1, pkc = w & 1;
  const int prow = pmt * 32 + l31;                        // row within 128-row block
  const int pat32 = 2 * at + (prow >> 6), pr6 = prow & 63;
  const unsigned* mrow = (const unsigned*)(ws + MW_OFF) +
                         (((size_t)(z * 32 + pat32)) << 12) + (pr6 & 15) * 4 + ((pr6 >> 4) & 3);
  const int pshift = pkc * 16 + h8;

  f32x16 acc[4];
#pragma unroll
  for (int mt = 0; mt < 4; ++mt)
#pragma unroll
    for (int r = 0; r < 16; ++r) acc[mt][r] = 0.f;

  bf16x8 Bf[4][2];                              // 4-deep register B pipeline
#pragma unroll
  for (int sl = 0; sl < 4; ++sl) {
    Bf[sl][0] = *(const bf16x8*)(bpz + (size_t)sl * 2048 + (size_t)lane * 16);
    Bf[sl][1] = *(const bf16x8*)(bpz + (size_t)sl * 2048 + 1024 + (size_t)lane * 16);
  }

  unsigned M[8];
#pragma unroll
  for (int i = 0; i < 8; ++i) M[i] = mrow[(size_t)i * 64];
  // produce group 0 -> ab0
#pragma unroll
  for (int i = 0; i < 8; ++i)
    *(bf16x8*)(ab0 + ((i * 8 + w) << 10) + (size_t)lane * 16) =
        unpack_mask((M[i] >> pshift) & 0xFFu);
  __syncthreads();

  for (int g = 0; g < 8; ++g) {
    unsigned char* const cur = (g & 1) ? ab1 : ab0;
    unsigned char* const nxt = (g & 1) ? ab0 : ab1;
    const int sbase = g * 8;
    const bool prod = (g < 7);
    if (prod) {
#pragma unroll
      for (int i = 0; i < 8; ++i) M[i] = mrow[(size_t)(sbase + 8 + i) * 64];
    }
#pragma unroll
    for (int i = 0; i < 8; ++i) {
      const int S = sbase + i;
      bf16x8 Af[4][2];
#pragma unroll
      for (int mt = 0; mt < 4; ++mt)
#pragma unroll
        for (int kc = 0; kc < 2; ++kc)
          Af[mt][kc] = *(const bf16x8*)(cur + ((i * 8 + mt * 2 + kc) << 10) + (size_t)lane * 16);
#pragma unroll
      for (int kc = 0; kc < 2; ++kc)
#pragma unroll
        for (int mt = 0; mt < 4; ++mt)
          acc[mt] = __builtin_amdgcn_mfma_f32_32x32x16_bf16(Af[mt][kc], Bf[i & 3][kc],
                                                            acc[mt], 0, 0, 0);
      const int sp = S + 4 > 63 ? 63 : S + 4;
      Bf[i & 3][0] = *(const bf16x8*)(bpz + (size_t)sp * 2048 + (size_t)lane * 16);
      Bf[i & 3][1] = *(const bf16x8*)(bpz + (size_t)sp * 2048 + 1024 + (size_t)lane * 16);
      if (prod)
        *(bf16x8*)(nxt + ((i * 8 + w) << 10) + (size_t)lane * 16) =
            unpack_mask((M[i] >> pshift) & 0xFFu);
    }
    __syncthreads();
  }

  // ---- epilogue: acc -> Ct fp32 (32x32 C/D layout + XOR swizzle, row&63) ----
  {
    const int rh = 4 * (lane >> 5);
    const int col = 32 * w + l31;
#pragma unroll
    for (int mt = 0; mt < 4; ++mt)
#pragma unroll
      for (int r = 0; r < 16; ++r) {
        const int row = mt * 32 + (r & 3) + 8 * (r >> 2) + rh;
        Ct[row * 256 + (((col >> 2) ^ (row & 63)) << 2) + (col & 3)] = acc[mt][r];
      }
  }
  __syncthreads();

  {
    const int lm = 16 * w + n;                             // final-GEMM A row (0..127)
    bf16x8 Across[8];
#pragma unroll
    for (int kb = 0; kb < 8; ++kb) {
      const int c0 = (kb * 8 + quad * 2) ^ (lm & 63);
      const int c1 = (kb * 8 + quad * 2 + 1) ^ (lm & 63);
      const float4 f0 = *(const float4*)&Ct[lm * 256 + c0 * 4];
      const float4 f1 = *(const float4*)&Ct[lm * 256 + c1 * 4];
      Across[kb] = pack8(f0, f1);
    }

    f32x4 mn[4], V[12];
#pragma unroll
    for (int i = 0; i < 4; ++i)
#pragma unroll
      for (int r = 0; r < 4; ++r) mn[i][r] = 0.f;
#pragma unroll
    for (int i = 0; i < 12; ++i)
#pragma unroll
      for (int r = 0; r < 4; ++r) V[i][r] = 0.f;

    const unsigned char* w2f = ws + W2F_OFF;
    const unsigned char* wxf = ws + WXF_OFF;
#pragma unroll
    for (int kb = 0; kb < 6; ++kb)
#pragma unroll
      for (int cb = 0; cb < 4; ++cb) {
        const bf16x8 Bfr = *(const bf16x8*)(w2f + (size_t)(kb * 4 + cb) * 1024 + fragoff);
        mn[cb] = __builtin_amdgcn_mfma_f32_16x16x32_bf16(Across[kb], Bfr, mn[cb], 0, 0, 0);
      }
#pragma unroll
    for (int kb = 0; kb < 2; ++kb)
#pragma unroll
      for (int cb = 0; cb < 12; ++cb) {
        const bf16x8 Bfr = *(const bf16x8*)(wxf + (size_t)(kb * 12 + cb) * 1024 + fragoff);
        V[cb] = __builtin_amdgcn_mfma_f32_16x16x32_bf16(Across[6 + kb], Bfr, V[cb], 0, 0, 0);
      }

#pragma unroll
    for (int r = 0; r < 4; ++r) {
      const int af = a0 + 16 * w + quad * 4 + r;           // C/D row = quad*4 + r
      const float g0 = geom[((size_t)z * NPTS + af) * 3 + 0];
      const float g1 = geom[((size_t)z * NPTS + af) * 3 + 1];
      const float g2 = geom[((size_t)z * NPTS + af) * 3 + 2];
#pragma unroll
      for (int cb = 0; cb < 4; ++cb) {
        const float v = mn[cb][r] - g0 * V[cb][r] - g1 * V[cb + 4][r] - g2 * V[cb + 8][r];
        out[((size_t)z * NPTS + af) * 64 + cb * 16 + n] = v;
      }
    }
  }
}

extern "C" void kernel_launch(void* const* d_in, const int* in_sizes, int n_in,
                              void* d_out, int out_size, void* d_ws, size_t ws_size,
                              hipStream_t stream) {
  const float* feat = (const float*)d_in[0];  // [8,2048,64]
  const float* geom = (const float*)d_in[1];  // [8,2048,3]
  const float* Wk   = (const float*)d_in[2];  // [3,64,64]
  float* out = (float*)d_out;                 // [8,2048,64] fp32
  unsigned char* ws = (unsigned char*)d_ws;   // ~12.4 MB used

  k1_prep<<<dim3(514), 256, 0, stream>>>(feat, geom, Wk, ws);
  k2_gemm<<<dim3(128), 512, 0, stream>>>(geom, ws, out);
}

// Round 3
// 95.351 us; speedup vs baseline: 1.1928x; 1.1928x over previous
//
#include <hip/hip_runtime.h>
#include <stdint.h>

#define NPTS 2048

// ---- workspace layout (bytes) ----
// Bp fragment-ordered for 32x32x16 MFMA: [z][cb=8][s=64][kc=2][frag 1KB].
// cb = global-col>>5 (256 cols = {f*gx,f*gy,f*gz,f} x 64j); kc = b-halfchunk (16 b each).
// Frag lane l (l&31 = col within 32-strip, l>>5 = k-half) holds 8 bf16 at k = (l>>5)*8..+8.
#define BP_OFF    0ULL
#define BP_BYTES  (8ULL * 8 * 64 * 2 * 1024)   // 8 MB
#define W2F_OFF   (BP_OFF + BP_BYTES)
#define W2F_BYTES (24ULL * 1024)               // frags kb0..5 x cb0..3
#define WXF_OFF   (W2F_OFF + W2F_BYTES)
#define WXF_BYTES (24ULL * 1024)               // frags kb0..1 x cb0..11
// Mask words: [z][at=32][kw=64][64 dwords]; dword (r&15)*4+((r>>4)&3) = word for row r.
#define MW_OFF    (WXF_OFF + WXF_BYTES)
#define MW_BYTES  (8ULL * 32 * 64 * 256)       // 4 MB  (total ~12.4 MB)

typedef __attribute__((ext_vector_type(8))) short bf16x8;
typedef __attribute__((ext_vector_type(4))) float f32x4;
typedef __attribute__((ext_vector_type(16))) float f32x16;
typedef __attribute__((ext_vector_type(4))) unsigned int u32x4;

__device__ __forceinline__ unsigned f2bf(float f) {
  union { float f; unsigned u; } v; v.f = f;
  return (v.u + 0x7FFFu + ((v.u >> 16) & 1u)) >> 16;  // RNE
}

__device__ __forceinline__ bf16x8 pack8(const float4 a, const float4 b) {
  u32x4 r;
  r[0] = f2bf(a.x) | (f2bf(a.y) << 16);
  r[1] = f2bf(a.z) | (f2bf(a.w) << 16);
  r[2] = f2bf(b.x) | (f2bf(b.y) << 16);
  r[3] = f2bf(b.z) | (f2bf(b.w) << 16);
  union { u32x4 u; bf16x8 h; } c; c.u = r; return c.h;
}

// 8 mask bits -> 8 bf16 (1.0/0.0): bit-deposit mul + v_perm + mul. (R9-verified)
__device__ __forceinline__ bf16x8 unpack_mask(unsigned mq) {
  const unsigned dep0 = ((mq & 15u) * 0x204081u) & 0x01010101u;        // bits0-3 -> bytes
  const unsigned dep1 = (((mq >> 4) & 15u) * 0x204081u) & 0x01010101u; // bits4-7
  u32x4 aw;
  aw[0] = __builtin_amdgcn_perm(dep0, 0u, 0x0C050C04u) * 0x3F80u;
  aw[1] = __builtin_amdgcn_perm(dep0, 0u, 0x0C070C06u) * 0x3F80u;
  aw[2] = __builtin_amdgcn_perm(dep1, 0u, 0x0C050C04u) * 0x3F80u;
  aw[3] = __builtin_amdgcn_perm(dep1, 0u, 0x0C070C06u) * 0x3F80u;
  union { u32x4 u; bf16x8 h; } cv; cv.u = aw;
  return cv.h;
}

// ========== K1: Bp frags (32x32x16 layout) + weight frags + mask bitwords (verified) ==========
__global__ __launch_bounds__(256, 2) void k1_prep(const float* __restrict__ feat,
                                                  const float* __restrict__ geom,
                                                  const float* __restrict__ Wk,
                                                  unsigned char* __restrict__ ws) {
  const int blk = blockIdx.x, t = threadIdx.x;
  if (blk < 512) {
    const int z = blk >> 6, s = blk & 63;       // 32 b-points per s-chunk
    __shared__ float FT[64][37];                // F^T[j][k]
    __shared__ float g[96];                     // b-geometry [32][3]
    __shared__ float gxp[2048], gyp[2048], gzp[2048];  // z geometry, swizzled p'=(p&7)*256+(p>>3)
    const float* fz = feat + ((size_t)z * NPTS + s * 32) * 64;
    const float* gz = geom + (size_t)z * NPTS * 3;
    {
      const int row = t >> 3, j0 = (t & 7) << 3;
      const float4 v0 = *(const float4*)&fz[row * 64 + j0];
      const float4 v1 = *(const float4*)&fz[row * 64 + j0 + 4];
      FT[j0 + 0][row] = v0.x; FT[j0 + 1][row] = v0.y;
      FT[j0 + 2][row] = v0.z; FT[j0 + 3][row] = v0.w;
      FT[j0 + 4][row] = v1.x; FT[j0 + 5][row] = v1.y;
      FT[j0 + 6][row] = v1.z; FT[j0 + 7][row] = v1.w;
    }
    if (t < 96) g[t] = gz[s * 96 + t];
    {  // stage geometry planes: thread reads 24 contiguous floats (8 points)
      float v[24];
#pragma unroll
      for (int i = 0; i < 6; ++i) *(float4*)&v[i * 4] = *(const float4*)&gz[t * 24 + i * 4];
#pragma unroll
      for (int i = 0; i < 8; ++i) {
        const int pp = i * 256 + t;             // swizzled slot (conflict-free)
        gxp[pp] = v[i * 3 + 0]; gyp[pp] = v[i * 3 + 1]; gzp[pp] = v[i * 3 + 2];
      }
    }
    __syncthreads();

    {  // ---- Bp build, 32x32x16 B-frag layout ----
      const int w = t >> 6, L = t & 63;
      const int nn = L >> 2, k0 = (L & 3) * 8;
      const int j = w * 16 + nn;
      float f[8];
#pragma unroll
      for (int i = 0; i < 8; ++i) f[i] = FT[j][k0 + i];
      float gx[3][8];
#pragma unroll
      for (int x = 0; x < 3; ++x)
#pragma unroll
        for (int i = 0; i < 8; ++i) gx[x][i] = g[(k0 + i) * 3 + x];
      // 32x32 frag addressing: cb = it*2 + (w>>1); kc = k0>>4; lane = h*32 + (w&1)*16 + nn
      const int kc = (L & 3) >> 1, h = (L & 3) & 1;
      const int lane16 = h * 32 + (w & 1) * 16 + nn;
      unsigned char* base = ws + BP_OFF + (size_t)z * 1048576 + (size_t)(w >> 1) * 131072 +
                            (size_t)s * 2048 + (size_t)kc * 1024 + (size_t)lane16 * 16;
#pragma unroll
      for (int it = 0; it < 4; ++it) {          // x = it; col group it
        u32x4 pv;
#pragma unroll
        for (int p = 0; p < 4; ++p) {
          float f0 = f[2 * p], f1 = f[2 * p + 1];
          if (it < 3) { f0 *= gx[it][2 * p]; f1 *= gx[it][2 * p + 1]; }
          pv[p] = f2bf(f0) | (f2bf(f1) << 16);
        }
        *(u32x4*)(base + (size_t)it * 262144) = pv;   // cb step = 2 frag-groups = 256 KB
      }
    }

    {  // ---- mask bitwords: rows t*8..+8 vs b = s*32..+32 ----
      float ax[8], ay[8], az[8];
#pragma unroll
      for (int i = 0; i < 8; ++i) {
        const int pp = i * 256 + t;
        ax[i] = gxp[pp]; ay[i] = gyp[pp]; az[i] = gzp[pp];
      }
      unsigned bits[8] = {0, 0, 0, 0, 0, 0, 0, 0};
      for (int j = 0; j < 32; ++j) {
        const float bx = g[j * 3 + 0], by = g[j * 3 + 1], bz = g[j * 3 + 2];
#pragma unroll
        for (int i = 0; i < 8; ++i) {
          const float d0 = bx - ax[i], d1 = by - ay[i], d2 = bz - az[i];
          const float n2 = fmaf(d2, d2, fmaf(d1, d1, d0 * d0));
          bits[i] |= (n2 < 1.0f ? 1u : 0u) << j;
        }
      }
      unsigned int* mw = (unsigned int*)(ws + MW_OFF);
#pragma unroll
      for (int i = 0; i < 8; ++i) {
        const int r = t * 8 + i;
        mw[(((size_t)z * 32 + (r >> 6)) * 64 + s) * 64 + (r & 15) * 4 + ((r >> 4) & 3)] = bits[i];
      }
    }
  } else if (blk == 512) {   // W2F frags
    for (int e = t; e < 1536; e += 256) {
      const int frag = e >> 6, lp = e & 63, nn = lp >> 2, qd = lp & 3;
      const int kb = frag >> 2, cb = frag & 3;
      u32x4 pv;
#pragma unroll
      for (int p = 0; p < 4; ++p) {
        const int k0 = kb * 32 + qd * 8 + 2 * p;
        const float v0 = Wk[(k0 >> 6) * 4096 + (cb * 16 + nn) * 64 + (k0 & 63)];
        const float v1 = Wk[((k0 + 1) >> 6) * 4096 + (cb * 16 + nn) * 64 + ((k0 + 1) & 63)];
        pv[p] = f2bf(v0) | (f2bf(v1) << 16);
      }
      *(u32x4*)(ws + W2F_OFF + (size_t)frag * 1024 + lp * 16) = pv;
    }
  } else {                   // WXF frags
    for (int e = t; e < 1536; e += 256) {
      const int frag = e >> 6, lp = e & 63, nn = lp >> 2, qd = lp & 3;
      const int kb = frag / 12, cb = frag % 12, xi = cb * 16 + nn;
      u32x4 pv;
#pragma unroll
      for (int p = 0; p < 4; ++p) {
        const int k0 = kb * 32 + qd * 8 + 2 * p;
        const float v0 = Wk[(xi >> 6) * 4096 + (xi & 63) * 64 + k0];
        const float v1 = Wk[(xi >> 6) * 4096 + (xi & 63) * 64 + k0 + 1];
        pv[p] = f2bf(v0) | (f2bf(v1) << 16);
      }
      *(u32x4*)(ws + WXF_OFF + (size_t)frag * 1024 + lp * 16) = pv;
    }
  }
}

// ========== K2: R1 geometry + LDS-shared mask A-frags (full-occupancy producer/consumer) ==
// grid 256 = (z = bx&7 -> XCD-resident Bp, at = bx>>3). 512 thr = 8 waves, 64-row blocks.
// Wave w consumes ALL 4 A-frag types x its 32-col strip cb=w (same MFMA set as R1).
// A-frags produced cooperatively: wave w unpacks type (w&3) for steps (w>>2)*4..+4 of each
// 8-step group, at its own lane slot (bit-identical to the R1 private unpack). 32KB x2
// dbuf aliased with Ct; ONE barrier per 8 steps (9 total). B stays in the 4-deep reg pipe.
__global__ __launch_bounds__(512, 2) void k2_gemm(const float* __restrict__ geom,
                                                  const unsigned char* __restrict__ ws,
                                                  float* __restrict__ out) {
  __shared__ __align__(16) float Ct[64 * 256];            // 64 KB; K-loop aliases as A dbuf
  unsigned char* const abuf = (unsigned char*)Ct;         // [2][8 steps][4 types][1KB]

  const int t = threadIdx.x, lane = t & 63, w = t >> 6;   // w = 0..7
  const int l31 = lane & 31;
  const int h8 = (lane >> 5) << 3;                        // k-half shift (0 or 8)
  const int quad = (lane >> 4) & 3, n = lane & 15;        // epilogue 16x16 mapping
  const int fragoff = n * 64 + quad * 16;
  const int bx = blockIdx.x;
  const int z = bx & 7, at = bx >> 3, a0 = at * 64;

  const unsigned char* bpz = ws + BP_OFF + (size_t)z * 1048576 + (size_t)w * 131072;

  // producer: wave w -> frag type = w&3 (mt = type>>1, kc = type&1),
  // steps (w>>2)*4 .. +4 of each 8-step group, own lane slot.
  const int ptype = w & 3, pkc = ptype & 1;
  const int prow = (ptype >> 1) * 32 + l31;               // row within 64-row block
  const unsigned* mrow = (const unsigned*)(ws + MW_OFF) + (((size_t)(z * 32 + at)) << 12) +
                         (prow & 15) * 4 + ((prow >> 4) & 3);
  const int pshift = pkc * 16 + h8;
  const int psub = (w >> 2) * 4;                          // which 4 steps of the group

  f32x16 acc0, acc1;
#pragma unroll
  for (int r = 0; r < 16; ++r) { acc0[r] = 0.f; acc1[r] = 0.f; }

  bf16x8 Bf[4][2];                              // 4-deep register B pipeline
#pragma unroll
  for (int sl = 0; sl < 4; ++sl) {
    Bf[sl][0] = *(const bf16x8*)(bpz + (size_t)sl * 2048 + (size_t)lane * 16);
    Bf[sl][1] = *(const bf16x8*)(bpz + (size_t)sl * 2048 + 1024 + (size_t)lane * 16);
  }

  unsigned M[4];
#pragma unroll
  for (int j = 0; j < 4; ++j) M[j] = mrow[(size_t)(psub + j) * 64];
  // produce group 0 into buffer 0
#pragma unroll
  for (int j = 0; j < 4; ++j)
    *(bf16x8*)(abuf + (((psub + j) * 4 + ptype) << 10) + (size_t)lane * 16) =
        unpack_mask((M[j] >> pshift) & 0xFFu);
  __syncthreads();

  for (int g = 0; g < 8; ++g) {
    unsigned char* const cur = abuf + (size_t)(g & 1) * 32768;
    unsigned char* const nxt = abuf + (size_t)((g & 1) ^ 1) * 32768;
    const bool prod = (g < 7);
    if (prod) {
#pragma unroll
      for (int j = 0; j < 4; ++j) M[j] = mrow[(size_t)((g + 1) * 8 + psub + j) * 64];
    }
#pragma unroll
    for (int i = 0; i < 8; ++i) {
      const int S = g * 8 + i;
      // A-frag slots: i*4 + type, type = mt*2 + kc
      const bf16x8 A00 = *(const bf16x8*)(cur + ((i * 4 + 0) << 10) + (size_t)lane * 16);
      const bf16x8 A01 = *(const bf16x8*)(cur + ((i * 4 + 1) << 10) + (size_t)lane * 16);
      const bf16x8 A10 = *(const bf16x8*)(cur + ((i * 4 + 2) << 10) + (size_t)lane * 16);
      const bf16x8 A11 = *(const bf16x8*)(cur + ((i * 4 + 3) << 10) + (size_t)lane * 16);
      // same accumulation order as R1: kc0 (both mt), then kc1
      acc0 = __builtin_amdgcn_mfma_f32_32x32x16_bf16(A00, Bf[i & 3][0], acc0, 0, 0, 0);
      acc1 = __builtin_amdgcn_mfma_f32_32x32x16_bf16(A10, Bf[i & 3][0], acc1, 0, 0, 0);
      acc0 = __builtin_amdgcn_mfma_f32_32x32x16_bf16(A01, Bf[i & 3][1], acc0, 0, 0, 0);
      acc1 = __builtin_amdgcn_mfma_f32_32x32x16_bf16(A11, Bf[i & 3][1], acc1, 0, 0, 0);
      const int sp = S + 4 > 63 ? 63 : S + 4;
      Bf[i & 3][0] = *(const bf16x8*)(bpz + (size_t)sp * 2048 + (size_t)lane * 16);
      Bf[i & 3][1] = *(const bf16x8*)(bpz + (size_t)sp * 2048 + 1024 + (size_t)lane * 16);
      if (prod && i < 4)
        *(bf16x8*)(nxt + (((psub + i) * 4 + ptype) << 10) + (size_t)lane * 16) =
            unpack_mask((M[i] >> pshift) & 0xFFu);
    }
    __syncthreads();
  }

  // ---- epilogue: acc -> Ct fp32 (32x32 C/D layout + verified XOR swizzle) ----
  {
    const int rh = 4 * (lane >> 5);
    const int col = 32 * w + l31;
#pragma unroll
    for (int r = 0; r < 16; ++r) {
      const int row = (r & 3) + 8 * (r >> 2) + rh;         // 32x32 C/D: rows 0..31
      Ct[row * 256 + (((col >> 2) ^ row) << 2) + (col & 3)] = acc0[r];
      const int row1 = row + 32;
      Ct[row1 * 256 + (((col >> 2) ^ row1) << 2) + (col & 3)] = acc1[r];
    }
  }
  __syncthreads();

  if (w < 4) {
    const int lm = 16 * w + n;                             // final-GEMM A row
    bf16x8 Across[8];
#pragma unroll
    for (int kb = 0; kb < 8; ++kb) {
      const int c0 = (kb * 8 + quad * 2) ^ lm;
      const int c1 = (kb * 8 + quad * 2 + 1) ^ lm;
      const float4 f0 = *(const float4*)&Ct[lm * 256 + c0 * 4];
      const float4 f1 = *(const float4*)&Ct[lm * 256 + c1 * 4];
      Across[kb] = pack8(f0, f1);
    }

    f32x4 mn[4], V[12];
#pragma unroll
    for (int i = 0; i < 4; ++i)
#pragma unroll
      for (int r = 0; r < 4; ++r) mn[i][r] = 0.f;
#pragma unroll
    for (int i = 0; i < 12; ++i)
#pragma unroll
      for (int r = 0; r < 4; ++r) V[i][r] = 0.f;

    const unsigned char* w2f = ws + W2F_OFF;
    const unsigned char* wxf = ws + WXF_OFF;
#pragma unroll
    for (int kb = 0; kb < 6; ++kb)
#pragma unroll
      for (int cb = 0; cb < 4; ++cb) {
        const bf16x8 Bfr = *(const bf16x8*)(w2f + (size_t)(kb * 4 + cb) * 1024 + fragoff);
        mn[cb] = __builtin_amdgcn_mfma_f32_16x16x32_bf16(Across[kb], Bfr, mn[cb], 0, 0, 0);
      }
#pragma unroll
    for (int kb = 0; kb < 2; ++kb)
#pragma unroll
      for (int cb = 0; cb < 12; ++cb) {
        const bf16x8 Bfr = *(const bf16x8*)(wxf + (size_t)(kb * 12 + cb) * 1024 + fragoff);
        V[cb] = __builtin_amdgcn_mfma_f32_16x16x32_bf16(Across[6 + kb], Bfr, V[cb], 0, 0, 0);
      }

#pragma unroll
    for (int r = 0; r < 4; ++r) {
      const int af = a0 + 16 * w + quad * 4 + r;           // C/D row = quad*4 + r
      const float g0 = geom[((size_t)z * NPTS + af) * 3 + 0];
      const float g1 = geom[((size_t)z * NPTS + af) * 3 + 1];
      const float g2 = geom[((size_t)z * NPTS + af) * 3 + 2];
#pragma unroll
      for (int cb = 0; cb < 4; ++cb) {
        const float v = mn[cb][r] - g0 * V[cb][r] - g1 * V[cb + 4][r] - g2 * V[cb + 8][r];
        out[((size_t)z * NPTS + af) * 64 + cb * 16 + n] = v;
      }
    }
  }
}

extern "C" void kernel_launch(void* const* d_in, const int* in_sizes, int n_in,
                              void* d_out, int out_size, void* d_ws, size_t ws_size,
                              hipStream_t stream) {
  const float* feat = (const float*)d_in[0];  // [8,2048,64]
  const float* geom = (const float*)d_in[1];  // [8,2048,3]
  const float* Wk   = (const float*)d_in[2];  // [3,64,64]
  float* out = (float*)d_out;                 // [8,2048,64] fp32
  unsigned char* ws = (unsigned char*)d_ws;   // ~12.4 MB used

  k1_prep<<<dim3(514), 256, 0, stream>>>(feat, geom, Wk, ws);
  k2_gemm<<<dim3(256), 512, 0, stream>>>(geom, ws, out);
}